// Round 5
// baseline (437.210 us; speedup 1.0000x reference)
//
#include <hip/hip_runtime.h>
#include <math.h>

#define B 128
#define N 512
#define H 512

typedef __attribute__((ext_vector_type(8))) short short8;
typedef __attribute__((ext_vector_type(4))) float floatx4;

typedef const __attribute__((address_space(1))) unsigned int* gas_t;
typedef __attribute__((address_space(3))) unsigned int* las_t;

// async global->LDS 16B (wave-uniform base + lane*16; our lds addr IS linear in lane)
__device__ __forceinline__ void gl16(const void* g, void* l){
    __builtin_amdgcn_global_load_lds((gas_t)g, (las_t)l, 16, 0, 0);
}

__device__ __forceinline__ float sigmoidf_(float x){ return 1.0f/(1.0f+__expf(-x)); }

// tanh(x) = 1 - 2/(1+e^{2x}): ~6 VALU (1 exp, 1 rcp), saturates correctly both ends
__device__ __forceinline__ float fast_tanh(float x){
    float e = __expf(2.0f*x);
    return 1.0f - __fdividef(2.0f, 1.0f + e);
}

// fp32 -> bf16 RNE
__device__ __forceinline__ unsigned f2bf1(float f){
    unsigned u = __float_as_uint(f);
    u += 0x7FFFu + ((u>>16)&1u);
    return u>>16;
}
__device__ __forceinline__ unsigned pk2(float a, float b){
    return f2bf1(a) | (f2bf1(b)<<16);
}

// ===== cast: weights (6656 rows, 4 rows/block vectorized) + small acts (128 blocks) =====
__global__ __launch_bounds__(256) void k_cast_small(
    const float* __restrict__ encW, const float* __restrict__ tgtW,
    const float* __restrict__ ptrW, const float* __restrict__ wih,
    const float* __restrict__ whh,
    const float* __restrict__ dec, const float* __restrict__ lhh,
    const float* __restrict__ tgt, const float* __restrict__ sem,
    unsigned short* __restrict__ We_s, unsigned short* __restrict__ Wt_s,
    unsigned short* __restrict__ Wp_s, unsigned short* __restrict__ We_d,
    unsigned short* __restrict__ Wt_d, unsigned short* __restrict__ Wp_c,
    unsigned short* __restrict__ Wp_e, unsigned short* __restrict__ Wih_b,
    unsigned short* __restrict__ Whh_b,
    unsigned short* __restrict__ Xbf, unsigned short* __restrict__ Hbf,
    unsigned short* __restrict__ Tbf, unsigned short* __restrict__ Sbf)
{
    int r = blockIdx.x, t = threadIdx.x;
    if (r < 1664){
        int gr = r*4 + (t>>6);          // weight-row 0..6655, wave-uniform
        int col = (t&63)*8;
        const float* src; unsigned short* dst; int pitch, off, row;
        if (gr < 512)      { src=encW; dst=We_s; pitch=2*H; off=0;   row=gr; }
        else if (gr<1024)  { src=tgtW; dst=Wt_s; pitch=2*H; off=0;   row=gr-512; }
        else if (gr<1536)  { src=ptrW; dst=Wp_s; pitch=3*H; off=0;   row=gr-1024; }
        else if (gr<2048)  { src=encW; dst=We_d; pitch=2*H; off=H;   row=gr-1536; }
        else if (gr<2560)  { src=tgtW; dst=Wt_d; pitch=2*H; off=H;   row=gr-2048; }
        else if (gr<3072)  { src=ptrW; dst=Wp_c; pitch=3*H; off=H;   row=gr-2560; }
        else if (gr<3584)  { src=ptrW; dst=Wp_e; pitch=3*H; off=2*H; row=gr-3072; }
        else if (gr<5120)  { src=wih;  dst=Wih_b;pitch=H;   off=0;   row=gr-3584; }
        else               { src=whh;  dst=Whh_b;pitch=H;   off=0;   row=gr-5120; }
        const float* s8 = &src[(size_t)row*pitch + off + col];
        float4 lo = *(const float4*)s8;
        float4 hi = *(const float4*)(s8+4);
        uint4 p;
        p.x = pk2(lo.x,lo.y); p.y = pk2(lo.z,lo.w);
        p.z = pk2(hi.x,hi.y); p.w = pk2(hi.z,hi.w);
        *(uint4*)&dst[(size_t)row*H + col] = p;
    } else {
        int blk = r - 1664; int mat = blk >> 5;
        const float* src = mat==0?dec : mat==1?lhh : mat==2?tgt : sem;
        unsigned short* dst = mat==0?Xbf : mat==1?Hbf : mat==2?Tbf : Sbf;
        size_t i = ((size_t)(blk&31)*256 + t)*8;
        float4 lo = *(const float4*)&src[i];
        float4 hi = *(const float4*)&src[i+4];
        uint4 p;
        p.x = pk2(lo.x,lo.y); p.y = pk2(lo.z,lo.w);
        p.z = pk2(hi.x,hi.y); p.w = pk2(hi.z,hi.w);
        *(uint4*)&dst[i] = p;
    }
}

// ===== shared 128x128x512 bf16 MFMA tile: C = A @ B^T (async LDS staging, K=64) =====
__device__ __forceinline__ void gemm128_tile(
    const unsigned short* __restrict__ Ab,   // 128 x 512 row-major bf16
    const unsigned short* __restrict__ Bb,   // 128 x 512 row-major bf16
    float* __restrict__ C, int ldc)
{
    __shared__ __align__(16) unsigned short As[128*64];
    __shared__ __align__(16) unsigned short Bs[128*64];
    int t = threadIdx.x;
    int lane = t & 63, wave = t >> 6;
    int wy = wave >> 1, wx = wave & 1;
    int li = lane & 15, quad = lane >> 4;

    floatx4 acc[4][4];
    #pragma unroll
    for (int i=0;i<4;++i)
      #pragma unroll
      for (int j=0;j<4;++j) acc[i][j] = (floatx4)(0.0f);

    for (int kt=0; kt<8; ++kt){
        int k0 = kt*64;
        #pragma unroll
        for (int c=0;c<4;++c){
            int s = c*256 + t;
            int row = s >> 3;
            int kb = (s & 7) ^ (row & 7);
            gl16(&Ab[(size_t)row*512 + k0 + kb*8], &As[(size_t)s*8]);
            gl16(&Bb[(size_t)row*512 + k0 + kb*8], &Bs[(size_t)s*8]);
        }
        __syncthreads();
        #pragma unroll
        for (int ks=0;ks<2;++ks){
            short8 af[4], bg[4];
            #pragma unroll
            for (int i=0;i<4;++i){
                int m = wy*64 + i*16 + li;
                int kb = (ks*4 + quad) ^ (m&7);
                af[i] = *(const short8*)&As[m*64 + kb*8];
            }
            #pragma unroll
            for (int j=0;j<4;++j){
                int h = wx*64 + j*16 + li;
                int kb = (ks*4 + quad) ^ (h&7);
                bg[j] = *(const short8*)&Bs[h*64 + kb*8];
            }
            #pragma unroll
            for (int i=0;i<4;++i)
              #pragma unroll
              for (int j=0;j<4;++j)
                acc[i][j] = __builtin_amdgcn_mfma_f32_16x16x32_bf16(af[i], bg[j], acc[i][j], 0,0,0);
        }
        __syncthreads();
    }
    #pragma unroll
    for (int i=0;i<4;++i)
      #pragma unroll
      for (int j=0;j<4;++j)
        #pragma unroll
        for (int rg=0;rg<4;++rg){
            int m = wy*64 + i*16 + quad*4 + rg;
            int n = wx*64 + j*16 + li;
            C[(size_t)m*ldc + n] = acc[i][j][rg];
        }
}

// ===== K-slice variant: kt in [ktbeg,ktend), atomicAdd combine (for critical-path minis) =====
__device__ __forceinline__ void gemm128_kslice(
    const unsigned short* __restrict__ Ab,
    const unsigned short* __restrict__ Bb,
    float* __restrict__ C, int ldc, int ktbeg, int ktend)
{
    __shared__ __align__(16) unsigned short As[128*64];
    __shared__ __align__(16) unsigned short Bs[128*64];
    int t = threadIdx.x;
    int lane = t & 63, wave = t >> 6;
    int wy = wave >> 1, wx = wave & 1;
    int li = lane & 15, quad = lane >> 4;

    floatx4 acc[4][4];
    #pragma unroll
    for (int i=0;i<4;++i)
      #pragma unroll
      for (int j=0;j<4;++j) acc[i][j] = (floatx4)(0.0f);

    for (int kt=ktbeg; kt<ktend; ++kt){
        int k0 = kt*64;
        #pragma unroll
        for (int c=0;c<4;++c){
            int s = c*256 + t;
            int row = s >> 3;
            int kb = (s & 7) ^ (row & 7);
            gl16(&Ab[(size_t)row*512 + k0 + kb*8], &As[(size_t)s*8]);
            gl16(&Bb[(size_t)row*512 + k0 + kb*8], &Bs[(size_t)s*8]);
        }
        __syncthreads();
        #pragma unroll
        for (int ks=0;ks<2;++ks){
            short8 af[4], bg[4];
            #pragma unroll
            for (int i=0;i<4;++i){
                int m = wy*64 + i*16 + li;
                int kb = (ks*4 + quad) ^ (m&7);
                af[i] = *(const short8*)&As[m*64 + kb*8];
            }
            #pragma unroll
            for (int j=0;j<4;++j){
                int h = wx*64 + j*16 + li;
                int kb = (ks*4 + quad) ^ (h&7);
                bg[j] = *(const short8*)&Bs[h*64 + kb*8];
            }
            #pragma unroll
            for (int i=0;i<4;++i)
              #pragma unroll
              for (int j=0;j<4;++j)
                acc[i][j] = __builtin_amdgcn_mfma_f32_16x16x32_bf16(af[i], bg[j], acc[i][j], 0,0,0);
        }
        __syncthreads();
    }
    #pragma unroll
    for (int i=0;i<4;++i)
      #pragma unroll
      for (int j=0;j<4;++j)
        #pragma unroll
        for (int rg=0;rg<4;++rg){
            int m = wy*64 + i*16 + quad*4 + rg;
            int n = wx*64 + j*16 + li;
            atomicAdd(&C[(size_t)m*ldc + n], acc[i][j][rg]);
        }
}

// fp32-A K-slice (inline cvt staging), atomicAdd combine
__device__ __forceinline__ void gemm128_kslice_f32A(
    const float* __restrict__ Af,
    const unsigned short* __restrict__ Bb,
    float* __restrict__ C, int ldc, int ktbeg, int ktend)
{
    __shared__ __align__(16) unsigned short As[128*64];
    __shared__ __align__(16) unsigned short Bs[128*64];
    int t = threadIdx.x;
    int lane = t & 63, wave = t >> 6;
    int wy = wave >> 1, wx = wave & 1;
    int li = lane & 15, quad = lane >> 4;

    floatx4 acc[4][4];
    #pragma unroll
    for (int i=0;i<4;++i)
      #pragma unroll
      for (int j=0;j<4;++j) acc[i][j] = (floatx4)(0.0f);

    for (int kt=ktbeg; kt<ktend; ++kt){
        int k0 = kt*64;
        #pragma unroll
        for (int c=0;c<4;++c){
            int s = c*256 + t;
            int row = s >> 3;
            int kb = (s & 7) ^ (row & 7);
            gl16(&Bb[(size_t)row*512 + k0 + kb*8], &Bs[(size_t)s*8]);
            const float* src = Af + (size_t)row*512 + k0 + kb*8;
            float4 lo = *(const float4*)src;
            float4 hi = *(const float4*)(src+4);
            uint4 p;
            p.x = pk2(lo.x,lo.y); p.y = pk2(lo.z,lo.w);
            p.z = pk2(hi.x,hi.y); p.w = pk2(hi.z,hi.w);
            *(uint4*)&As[(size_t)s*8] = p;
        }
        __syncthreads();
        #pragma unroll
        for (int ks=0;ks<2;++ks){
            short8 af[4], bg[4];
            #pragma unroll
            for (int i=0;i<4;++i){
                int m = wy*64 + i*16 + li;
                int kb = (ks*4 + quad) ^ (m&7);
                af[i] = *(const short8*)&As[m*64 + kb*8];
            }
            #pragma unroll
            for (int j=0;j<4;++j){
                int h = wx*64 + j*16 + li;
                int kb = (ks*4 + quad) ^ (h&7);
                bg[j] = *(const short8*)&Bs[h*64 + kb*8];
            }
            #pragma unroll
            for (int i=0;i<4;++i)
              #pragma unroll
              for (int j=0;j<4;++j)
                acc[i][j] = __builtin_amdgcn_mfma_f32_16x16x32_bf16(af[i], bg[j], acc[i][j], 0,0,0);
        }
        __syncthreads();
    }
    #pragma unroll
    for (int i=0;i<4;++i)
      #pragma unroll
      for (int j=0;j<4;++j)
        #pragma unroll
        for (int rg=0;rg<4;++rg){
            int m = wy*64 + i*16 + quad*4 + rg;
            int n = wx*64 + j*16 + li;
            atomicAdd(&C[(size_t)m*ldc + n], acc[i][j][rg]);
        }
}

// ---- mega kernel: GRU gates GEMM (24) + GRU-independent bias GEMMs (8) + A cast ----
__global__ __launch_bounds__(256,2) void k_mega(
    const unsigned short* __restrict__ Xbf, const unsigned short* __restrict__ Hbf,
    const unsigned short* __restrict__ Wih_b, const unsigned short* __restrict__ Whh_b,
    float* __restrict__ gx, float* __restrict__ gh,
    const unsigned short* __restrict__ Tbf, const unsigned short* __restrict__ Sbf,
    const unsigned short* __restrict__ Wt_d, const unsigned short* __restrict__ Wp_e,
    float* __restrict__ d_tgt, float* __restrict__ d_se,
    const float* __restrict__ A, unsigned short* __restrict__ Abf)
{
    int blk = blockIdx.x;
    if (blk < 32){
        const unsigned short *Ab, *Bb; float* C; int ldc;
        if (blk < 24){
            int mat = blk / 12, nt = blk % 12;
            Ab = mat ? Hbf : Xbf;
            Bb = (mat ? Whh_b : Wih_b) + (size_t)nt*128*512;
            C = (mat ? gh : gx) + nt*128;
            ldc = 3*H;
        } else {
            int sub = blk - 24; int mat = sub >> 2, nt = sub & 3;
            Ab = mat==0 ? Tbf : Sbf;
            Bb = (mat==0 ? Wt_d : Wp_e) + (size_t)nt*128*512;
            C = (mat==0 ? d_tgt : d_se) + nt*128;
            ldc = H;
        }
        gemm128_tile(Ab, Bb, C, ldc);
    } else {
        int t = threadIdx.x;
        size_t i = ((size_t)(blk-32)*256 + t)*8;
        float4 lo = *(const float4*)&A[i];
        float4 hi = *(const float4*)&A[i+4];
        uint4 p;
        p.x = pk2(lo.x,lo.y); p.y = pk2(lo.z,lo.w);
        p.z = pk2(hi.x,hi.y); p.w = pk2(hi.z,hi.w);
        *(uint4*)&Abf[i] = p;
    }
}

// ---- GRU elementwise gates ----
__global__ __launch_bounds__(256) void k_gru_gate(const float* __restrict__ gx,
    const float* __restrict__ gh, const float* __restrict__ lhh,
    const float* __restrict__ bih, const float* __restrict__ bhh,
    float* __restrict__ out_hh, unsigned short* __restrict__ hnew_bf)
{
    int idx = blockIdx.x*256 + threadIdx.x;   // 0..65535
    int b = idx >> 9, k = idx & 511;
    const float* gxb = gx + (size_t)b*(3*H);
    const float* ghb = gh + (size_t)b*(3*H);
    float r = sigmoidf_(gxb[k]     + bih[k]     + ghb[k]     + bhh[k]);
    float z = sigmoidf_(gxb[H+k]   + bih[H+k]   + ghb[H+k]   + bhh[H+k]);
    float n = tanhf(gxb[2*H+k] + bih[2*H+k] + r*(ghb[2*H+k] + bhh[2*H+k]));
    float h = (1.f-z)*n + z*lhh[idx];
    out_hh[idx] = h;
    hnew_bf[idx] = (unsigned short)f2bf1(h);
}

// ---- enc bias GEMM: K-split x4 (grid 16) to shorten the GRU critical path ----
__global__ __launch_bounds__(256,2) void k_bias_enc(
    const unsigned short* __restrict__ HNbf, const unsigned short* __restrict__ We_d,
    float* __restrict__ d_enc)
{
    int nt = blockIdx.x & 3, ks = blockIdx.x >> 2;
    gemm128_kslice(HNbf, We_d + (size_t)nt*128*512, d_enc + nt*128, H, ks*2, ks*2+2);
}

// ---- pointer biases GEMM: K-split x4 (grid 32), fp32 ctx/ctxt staged inline ----
__global__ __launch_bounds__(256,2) void k_dptr_gemm(
    const float* __restrict__ ctx, const float* __restrict__ ctxt,
    const unsigned short* __restrict__ Wp_c,
    float* __restrict__ d_pe, float* __restrict__ d_pt)
{
    int blk = blockIdx.x;
    int mat = blk >> 4, sub = blk & 15;
    int nt = sub & 3, ks = sub >> 2;
    const float* Af = mat ? ctxt : ctx;
    const unsigned short* Bb = Wp_c + (size_t)nt*128*512;
    float* C = (mat ? d_pt : d_pe) + nt*128;
    gemm128_kslice_f32A(Af, Bb, C, H, ks*2, ks*2+2);
}

// ---- fused enc+tgt scores: grid 512 (b x nt), ht loop inside, single-buffer K=64 ----
// (the R1 core: best measured structure, 104us, 0 conflicts)
template<bool BF16A>
__global__ __launch_bounds__(256,2) void k_scores_fused(
    const float* __restrict__ Af, const unsigned short* __restrict__ Abf,
    const unsigned short* __restrict__ We, const unsigned short* __restrict__ Wt,
    const float* __restrict__ d_enc, const float* __restrict__ d_tgt,
    const float* __restrict__ enc_v, const float* __restrict__ tgt_v,
    float* __restrict__ sc_e, float* __restrict__ sc_t)
{
    __shared__ __align__(16) unsigned short As[128*64];
    __shared__ __align__(16) unsigned short Be[128*64];
    __shared__ __align__(16) unsigned short Bt[128*64];
    __shared__ float red_e[2][128], red_t[2][128];
    int blk = blockIdx.x;
    int b = blk >> 2; int nt = blk & 3;
    int n0 = nt*128;
    int t = threadIdx.x;
    int lane = t & 63, wave = t >> 6;
    int wy = wave >> 1, wx = wave & 1;
    int li = lane & 15, quad = lane >> 4;

    float nse[4][4], nst[4][4];
    #pragma unroll
    for (int i=0;i<4;++i)
      #pragma unroll
      for (int rg=0;rg<4;++rg){ nse[i][rg]=0.f; nst[i][rg]=0.f; }

    for (int ht=0; ht<4; ++ht){
        int hb = ht*128;
        floatx4 acc_e[4][4], acc_t[4][4];
        #pragma unroll
        for (int i=0;i<4;++i)
          #pragma unroll
          for (int j=0;j<4;++j){ acc_e[i][j]=(floatx4)(0.0f); acc_t[i][j]=(floatx4)(0.0f); }

        for (int kt=0; kt<8; ++kt){
            int k0 = kt*64;
            #pragma unroll
            for (int c=0;c<4;++c){
                int s = c*256 + t;
                int row = s >> 3;
                int kb = (s & 7) ^ (row & 7);
                if constexpr (BF16A){
                    gl16(&Abf[(size_t)(b*N+n0+row)*H + k0 + kb*8], &As[(size_t)s*8]);
                } else {
                    const float* src = Af + (size_t)(b*N+n0+row)*H + k0 + kb*8;
                    float4 lo = *(const float4*)src;
                    float4 hi = *(const float4*)(src+4);
                    uint4 p;
                    p.x = pk2(lo.x,lo.y); p.y = pk2(lo.z,lo.w);
                    p.z = pk2(hi.x,hi.y); p.w = pk2(hi.z,hi.w);
                    *(uint4*)&As[(size_t)s*8] = p;
                }
                gl16(&We[(size_t)(hb+row)*H + k0 + kb*8], &Be[(size_t)s*8]);
                gl16(&Wt[(size_t)(hb+row)*H + k0 + kb*8], &Bt[(size_t)s*8]);
            }
            __syncthreads();
            #pragma unroll
            for (int ks=0;ks<2;++ks){
                short8 af[4], be[4], bt[4];
                #pragma unroll
                for (int i=0;i<4;++i){
                    int m = wy*64 + i*16 + li;
                    int kb = (ks*4 + quad) ^ (m&7);
                    af[i] = *(const short8*)&As[m*64 + kb*8];
                }
                #pragma unroll
                for (int j=0;j<4;++j){
                    int h = wx*64 + j*16 + li;
                    int kb = (ks*4 + quad) ^ (h&7);
                    be[j] = *(const short8*)&Be[h*64 + kb*8];
                    bt[j] = *(const short8*)&Bt[h*64 + kb*8];
                }
                #pragma unroll
                for (int i=0;i<4;++i)
                  #pragma unroll
                  for (int j=0;j<4;++j){
                    acc_e[i][j] = __builtin_amdgcn_mfma_f32_16x16x32_bf16(af[i], be[j], acc_e[i][j], 0,0,0);
                    acc_t[i][j] = __builtin_amdgcn_mfma_f32_16x16x32_bf16(af[i], bt[j], acc_t[i][j], 0,0,0);
                  }
            }
            __syncthreads();
        }
        // epilogue for this h-tile: accumulate v*tanh(S+d) into per-lane partials
        #pragma unroll
        for (int j=0;j<4;++j){
            int hm = hb + wx*64 + j*16 + li;
            float dje = d_enc[b*H+hm], vje = enc_v[hm];
            float djt = d_tgt[b*H+hm], vjt = tgt_v[hm];
            #pragma unroll
            for (int i=0;i<4;++i)
              #pragma unroll
              for (int rg=0;rg<4;++rg){
                nse[i][rg] += vje * fast_tanh(acc_e[i][j][rg] + dje);
                nst[i][rg] += vjt * fast_tanh(acc_t[i][j][rg] + djt);
              }
        }
    }
    #pragma unroll
    for (int off=1; off<16; off<<=1)
      #pragma unroll
      for (int i=0;i<4;++i)
        #pragma unroll
        for (int rg=0;rg<4;++rg){
          nse[i][rg] += __shfl_xor(nse[i][rg], off);
          nst[i][rg] += __shfl_xor(nst[i][rg], off);
        }
    if (li==0){
        #pragma unroll
        for (int i=0;i<4;++i)
          #pragma unroll
          for (int rg=0;rg<4;++rg){
            red_e[wx][wy*64 + i*16 + quad*4 + rg] = nse[i][rg];
            red_t[wx][wy*64 + i*16 + quad*4 + rg] = nst[i][rg];
          }
    }
    __syncthreads();
    if (t < 128){
        sc_e[b*N + n0 + t] = red_e[0][t] + red_e[1][t];
    } else {
        int r2 = t - 128;
        sc_t[b*N + n0 + r2] = red_t[0][r2] + red_t[1][r2];
    }
}

// ---- fused softmax + context: grid 512 (b x col-quarter), direct store ----
template<bool BF16A>
__global__ __launch_bounds__(256) void k_smax_ctx(
    const float* __restrict__ Af, const unsigned short* __restrict__ Abf,
    const float* __restrict__ sc_e, const float* __restrict__ sc_t,
    float* __restrict__ ctx, float* __restrict__ ctxt)
{
    __shared__ float we[512], wt[512];
    __shared__ float buf[256];
    __shared__ float red[4][64][4];
    int b = blockIdx.x >> 2, q = blockIdx.x & 3;
    int t = threadIdx.x;

    {
        float x0 = sc_e[b*N+t], x1 = sc_e[b*N+t+256];
        float m = fmaxf(x0,x1);
        buf[t]=m; __syncthreads();
        for (int s2=128;s2>0;s2>>=1){ if(t<s2) buf[t]=fmaxf(buf[t],buf[t+s2]); __syncthreads(); }
        m = buf[0]; __syncthreads();
        float e0 = __expf(x0-m), e1 = __expf(x1-m);
        buf[t]=e0+e1; __syncthreads();
        for (int s2=128;s2>0;s2>>=1){ if(t<s2) buf[t]+=buf[t+s2]; __syncthreads(); }
        float inv = 1.0f/buf[0]; __syncthreads();
        we[t]=e0*inv; we[t+256]=e1*inv;
    }
    {
        float x0 = sc_t[b*N+t], x1 = sc_t[b*N+t+256];
        float m = fmaxf(x0,x1);
        buf[t]=m; __syncthreads();
        for (int s2=128;s2>0;s2>>=1){ if(t<s2) buf[t]=fmaxf(buf[t],buf[t+s2]); __syncthreads(); }
        m = buf[0]; __syncthreads();
        float e0 = __expf(x0-m), e1 = __expf(x1-m);
        buf[t]=e0+e1; __syncthreads();
        for (int s2=128;s2>0;s2>>=1){ if(t<s2) buf[t]+=buf[t+s2]; __syncthreads(); }
        float inv = 1.0f/buf[0]; __syncthreads();
        wt[t]=e0*inv; wt[t+256]=e1*inv;
    }
    __syncthreads();

    int p = t & 63, nq = t >> 6;
    int cp = q*64 + p;
    float ae0=0.f, ae1=0.f, at0=0.f, at1=0.f;
    if constexpr (BF16A){
        const unsigned* base = (const unsigned*)Abf + (size_t)(b*N + nq*128)*(H/2) + cp;
        for (int n=0;n<128;++n){
            unsigned u = base[(size_t)n*(H/2)];
            float lo = __uint_as_float(u<<16);
            float hi = __uint_as_float(u & 0xFFFF0000u);
            float e = we[nq*128+n], g = wt[nq*128+n];
            ae0 += e*lo; ae1 += e*hi; at0 += g*lo; at1 += g*hi;
        }
    } else {
        const float* base = Af + (size_t)(b*N + nq*128)*H + 2*cp;
        for (int n=0;n<128;++n){
            float2 v = *(const float2*)&base[(size_t)n*H];
            float e = we[nq*128+n], g = wt[nq*128+n];
            ae0 += e*v.x; ae1 += e*v.y; at0 += g*v.x; at1 += g*v.y;
        }
    }
    red[nq][p][0]=ae0; red[nq][p][1]=ae1; red[nq][p][2]=at0; red[nq][p][3]=at1;
    __syncthreads();
    if (t < 64){
        float s0=0.f,s1=0.f,s2=0.f,s3=0.f;
        #pragma unroll
        for (int k2=0;k2<4;++k2){
            s0+=red[k2][t][0]; s1+=red[k2][t][1]; s2+=red[k2][t][2]; s3+=red[k2][t][3];
        }
        int c2 = q*64 + t;
        ctx [(size_t)b*H + 2*c2]   = s0;
        ctx [(size_t)b*H + 2*c2+1] = s1;
        ctxt[(size_t)b*H + 2*c2]   = s2;
        ctxt[(size_t)b*H + 2*c2+1] = s3;
    }
}

// ---- pointer probs: grid 512 (b x nt), ht loop inside, single-buffer K=64 (R1 core) ----
template<bool BF16A>
__global__ __launch_bounds__(256,2) void k_probs_mfma(
    const float* __restrict__ Af, const unsigned short* __restrict__ Abf,
    const unsigned short* __restrict__ Wp,
    const float* __restrict__ d_pe, const float* __restrict__ d_pt,
    const float* __restrict__ d_se,
    const float* __restrict__ ptr_v, float* __restrict__ probs)
{
    __shared__ __align__(16) unsigned short As[128*64];
    __shared__ __align__(16) unsigned short Bs[128*64];
    __shared__ float red[2][128];
    int blk = blockIdx.x;
    int b = blk >> 2; int nt = blk & 3;
    int n0 = nt*128;

    int t = threadIdx.x;
    int lane = t & 63, wave = t >> 6;
    int wy = wave >> 1, wx = wave & 1;
    int li = lane & 15, quad = lane >> 4;

    float nsum[4][4];
    #pragma unroll
    for (int i=0;i<4;++i){ nsum[i][0]=0.f;nsum[i][1]=0.f;nsum[i][2]=0.f;nsum[i][3]=0.f; }

    for (int ht=0; ht<4; ++ht){
        int hb = ht*128;
        floatx4 acc[4][4];
        #pragma unroll
        for (int i=0;i<4;++i)
          #pragma unroll
          for (int j=0;j<4;++j) acc[i][j] = (floatx4)(0.0f);

        for (int kt=0; kt<8; ++kt){
            int k0 = kt*64;
            #pragma unroll
            for (int c=0;c<4;++c){
                int s = c*256 + t;
                int row = s >> 3;
                int kb = (s & 7) ^ (row & 7);
                if constexpr (BF16A){
                    gl16(&Abf[(size_t)(b*N+n0+row)*H + k0 + kb*8], &As[(size_t)s*8]);
                } else {
                    const float* src = Af + (size_t)(b*N+n0+row)*H + k0 + kb*8;
                    float4 lo = *(const float4*)src;
                    float4 hi = *(const float4*)(src+4);
                    uint4 p;
                    p.x = pk2(lo.x,lo.y); p.y = pk2(lo.z,lo.w);
                    p.z = pk2(hi.x,hi.y); p.w = pk2(hi.z,hi.w);
                    *(uint4*)&As[(size_t)s*8] = p;
                }
                gl16(&Wp[(size_t)(hb+row)*H + k0 + kb*8], &Bs[(size_t)s*8]);
            }
            __syncthreads();
            #pragma unroll
            for (int ks=0;ks<2;++ks){
                short8 af[4], bg[4];
                #pragma unroll
                for (int i=0;i<4;++i){
                    int m = wy*64 + i*16 + li;
                    int kb = (ks*4 + quad) ^ (m&7);
                    af[i] = *(const short8*)&As[m*64 + kb*8];
                }
                #pragma unroll
                for (int j=0;j<4;++j){
                    int h = wx*64 + j*16 + li;
                    int kb = (ks*4 + quad) ^ (h&7);
                    bg[j] = *(const short8*)&Bs[h*64 + kb*8];
                }
                #pragma unroll
                for (int i=0;i<4;++i)
                  #pragma unroll
                  for (int j=0;j<4;++j)
                    acc[i][j] = __builtin_amdgcn_mfma_f32_16x16x32_bf16(af[i], bg[j], acc[i][j], 0,0,0);
            }
            __syncthreads();
        }
        #pragma unroll
        for (int j=0;j<4;++j){
            int hm = hb + wx*64 + j*16 + li;
            float se = d_se[b*H + hm];
            float de = d_pe[b*H + hm] + se;
            float dt = d_pt[b*H + hm] + se;
            float vj = ptr_v[hm];
            #pragma unroll
            for (int i=0;i<4;++i)
              #pragma unroll
              for (int rg=0;rg<4;++rg){
                float s = acc[i][j][rg];
                nsum[i][rg] += vj * (5.0f*fast_tanh(s + de) + fast_tanh(s + dt));
              }
        }
    }
    #pragma unroll
    for (int off=1; off<16; off<<=1)
      #pragma unroll
      for (int i=0;i<4;++i)
        #pragma unroll
        for (int rg=0;rg<4;++rg)
          nsum[i][rg] += __shfl_xor(nsum[i][rg], off);
    if (li==0){
        #pragma unroll
        for (int i=0;i<4;++i)
          #pragma unroll
          for (int rg=0;rg<4;++rg)
            red[wx][wy*64 + i*16 + quad*4 + rg] = nsum[i][rg];
    }
    __syncthreads();
    if (t < 128)
        probs[b*N + n0 + t] = red[0][t] + red[1][t];
}

extern "C" void kernel_launch(void* const* d_in, const int* in_sizes, int n_in,
                              void* d_out, int out_size, void* d_ws, size_t ws_size,
                              hipStream_t stream)
{
    (void)in_sizes; (void)n_in; (void)out_size;
    const float* A    = (const float*)d_in[0];
    const float* sem  = (const float*)d_in[1];
    const float* dec  = (const float*)d_in[2];
    const float* tgt  = (const float*)d_in[3];
    const float* lhh  = (const float*)d_in[4];
    const float* ptrv = (const float*)d_in[5];
    const float* ptrW = (const float*)d_in[6];
    const float* encv = (const float*)d_in[7];
    const float* encW = (const float*)d_in[8];
    const float* tgtv = (const float*)d_in[9];
    const float* tgtW = (const float*)d_in[10];
    const float* wih  = (const float*)d_in[11];
    const float* whh  = (const float*)d_in[12];
    const float* bih  = (const float*)d_in[13];
    const float* bhh  = (const float*)d_in[14];

    float* probs_out = (float*)d_out;
    float* hh_out    = (float*)d_out + B*N;

    float* ws = (float*)d_ws;
    const size_t S = (size_t)B*H;          // 65536
    float* d_enc = ws;
    float* d_tgt = ws + S;
    float* d_se  = ws + 2*S;
    float* sc_e  = ws + 3*S;
    float* sc_t  = ws + 4*S;
    float* ctx   = ws + 5*S;
    float* ctxt  = ws + 6*S;
    float* d_pe  = ws + 9*S;
    float* d_pt  = ws + 10*S;
    float* gx    = ws + 11*S;              // 3S
    float* gh    = ws + 14*S;              // 3S
    unsigned short* bfb  = (unsigned short*)(ws + 17*S);
    const size_t WH = (size_t)H*H;         // 262144
    const size_t WG = (size_t)3*H*H;
    unsigned short* We_s  = bfb;
    unsigned short* Wt_s  = We_s + WH;
    unsigned short* Wp_s  = Wt_s + WH;
    unsigned short* We_d  = Wp_s + WH;
    unsigned short* Wt_d  = We_d + WH;
    unsigned short* Wp_c  = Wt_d + WH;
    unsigned short* Wp_e  = Wp_c + WH;
    unsigned short* Wih_b = Wp_e + WH;
    unsigned short* Whh_b = Wih_b + WG;
    unsigned short* Xbf   = Whh_b + WG;
    unsigned short* Hbf   = Xbf + S;
    unsigned short* Tbf   = Hbf + S;
    unsigned short* Sbf   = Tbf + S;
    unsigned short* HNbf  = Sbf + S;
    unsigned short* Abf   = HNbf + S;

    const size_t need_full = 17*S*sizeof(float)
        + (7*WH + 2*WG + 5*S + (size_t)B*N*H) * sizeof(unsigned short);
    const bool big = ws_size >= need_full;

    // K-split minis combine via atomics -> zero their outputs (tiny, overlaps cast)
    hipMemsetAsync(d_enc, 0, S*sizeof(float), stream);
    hipMemsetAsync(d_pe, 0, 2*S*sizeof(float), stream);

    // 1. weight + small-activation casts (vectorized: 4 rows/block)
    k_cast_small<<<1792, 256, 0, stream>>>(encW, tgtW, ptrW, wih, whh,
        dec, lhh, tgt, sem,
        We_s, Wt_s, Wp_s, We_d, Wt_d, Wp_c, Wp_e, Wih_b, Whh_b,
        Xbf, Hbf, Tbf, Sbf);

    // 2. GRU GEMMs + GRU-independent bias GEMMs, hidden under the A cast
    int castA_blocks = big ? (int)(((size_t)B*N*H)/(256*8)) : 0;   // 16384
    k_mega<<<32 + castA_blocks, 256, 0, stream>>>(Xbf, Hbf, Wih_b, Whh_b, gx, gh,
        Tbf, Sbf, Wt_d, Wp_e, d_tgt, d_se, A, Abf);

    // 3. GRU gates
    k_gru_gate<<<256, 256, 0, stream>>>(gx, gh, lhh, bih, bhh, hh_out, HNbf);

    // 4. d_enc, K-split x4 (16 blocks)
    k_bias_enc<<<16, 256, 0, stream>>>(HNbf, We_d, d_enc);

    // 5. fused scores (R1 single-buffer core), direct store
    if (big)
        k_scores_fused<true ><<<512, 256, 0, stream>>>(A, Abf, We_s, Wt_s, d_enc, d_tgt, encv, tgtv, sc_e, sc_t);
    else
        k_scores_fused<false><<<512, 256, 0, stream>>>(A, Abf, We_s, Wt_s, d_enc, d_tgt, encv, tgtv, sc_e, sc_t);

    // 6. softmax + context fused, direct store
    if (big)
        k_smax_ctx<true ><<<512, 256, 0, stream>>>(A, Abf, sc_e, sc_t, ctx, ctxt);
    else
        k_smax_ctx<false><<<512, 256, 0, stream>>>(A, Abf, sc_e, sc_t, ctx, ctxt);

    // 7. pointer bias GEMMs, K-split x4 (32 blocks)
    k_dptr_gemm<<<32, 256, 0, stream>>>(ctx, ctxt, Wp_c, d_pe, d_pt);

    // 8. pointer probs (R1 single-buffer core), direct store
    if (big)
        k_probs_mfma<true ><<<512, 256, 0, stream>>>(A, Abf, Wp_s, d_pe, d_pt, d_se, ptrv, probs_out);
    else
        k_probs_mfma<false><<<512, 256, 0, stream>>>(A, Abf, Wp_s, d_pe, d_pt, d_se, ptrv, probs_out);
}

// Round 6
// 409.453 us; speedup vs baseline: 1.0678x; 1.0678x over previous
//
#include <hip/hip_runtime.h>
#include <math.h>

#define B 128
#define N 512
#define H 512

typedef __attribute__((ext_vector_type(8))) short short8;
typedef __attribute__((ext_vector_type(4))) float floatx4;

typedef const __attribute__((address_space(1))) unsigned int* gas_t;
typedef __attribute__((address_space(3))) unsigned int* las_t;

// async global->LDS 16B (wave-uniform base + lane*16; our lds addr IS linear in lane)
__device__ __forceinline__ void gl16(const void* g, void* l){
    __builtin_amdgcn_global_load_lds((gas_t)g, (las_t)l, 16, 0, 0);
}

__device__ __forceinline__ float sigmoidf_(float x){ return 1.0f/(1.0f+__expf(-x)); }

// tanh(x) = 1 - 2/(1+e^{2x}): ~6 VALU (1 exp, 1 rcp), saturates correctly both ends
__device__ __forceinline__ float fast_tanh(float x){
    float e = __expf(2.0f*x);
    return 1.0f - __fdividef(2.0f, 1.0f + e);
}

// fp32 -> bf16 RNE
__device__ __forceinline__ unsigned f2bf1(float f){
    unsigned u = __float_as_uint(f);
    u += 0x7FFFu + ((u>>16)&1u);
    return u>>16;
}
__device__ __forceinline__ unsigned pk2(float a, float b){
    return f2bf1(a) | (f2bf1(b)<<16);
}

// ===== cast: weights (6656 rows, 4 rows/block vectorized) + small acts (128 blocks) =====
__global__ __launch_bounds__(256) void k_cast_small(
    const float* __restrict__ encW, const float* __restrict__ tgtW,
    const float* __restrict__ ptrW, const float* __restrict__ wih,
    const float* __restrict__ whh,
    const float* __restrict__ dec, const float* __restrict__ lhh,
    const float* __restrict__ tgt, const float* __restrict__ sem,
    unsigned short* __restrict__ We_s, unsigned short* __restrict__ Wt_s,
    unsigned short* __restrict__ Wp_s, unsigned short* __restrict__ We_d,
    unsigned short* __restrict__ Wt_d, unsigned short* __restrict__ Wp_c,
    unsigned short* __restrict__ Wp_e, unsigned short* __restrict__ Wih_b,
    unsigned short* __restrict__ Whh_b,
    unsigned short* __restrict__ Xbf, unsigned short* __restrict__ Hbf,
    unsigned short* __restrict__ Tbf, unsigned short* __restrict__ Sbf)
{
    int r = blockIdx.x, t = threadIdx.x;
    if (r < 1664){
        int gr = r*4 + (t>>6);          // weight-row 0..6655, wave-uniform
        int col = (t&63)*8;
        const float* src; unsigned short* dst; int pitch, off, row;
        if (gr < 512)      { src=encW; dst=We_s; pitch=2*H; off=0;   row=gr; }
        else if (gr<1024)  { src=tgtW; dst=Wt_s; pitch=2*H; off=0;   row=gr-512; }
        else if (gr<1536)  { src=ptrW; dst=Wp_s; pitch=3*H; off=0;   row=gr-1024; }
        else if (gr<2048)  { src=encW; dst=We_d; pitch=2*H; off=H;   row=gr-1536; }
        else if (gr<2560)  { src=tgtW; dst=Wt_d; pitch=2*H; off=H;   row=gr-2048; }
        else if (gr<3072)  { src=ptrW; dst=Wp_c; pitch=3*H; off=H;   row=gr-2560; }
        else if (gr<3584)  { src=ptrW; dst=Wp_e; pitch=3*H; off=2*H; row=gr-3072; }
        else if (gr<5120)  { src=wih;  dst=Wih_b;pitch=H;   off=0;   row=gr-3584; }
        else               { src=whh;  dst=Whh_b;pitch=H;   off=0;   row=gr-5120; }
        const float* s8 = &src[(size_t)row*pitch + off + col];
        float4 lo = *(const float4*)s8;
        float4 hi = *(const float4*)(s8+4);
        uint4 p;
        p.x = pk2(lo.x,lo.y); p.y = pk2(lo.z,lo.w);
        p.z = pk2(hi.x,hi.y); p.w = pk2(hi.z,hi.w);
        *(uint4*)&dst[(size_t)row*H + col] = p;
    } else {
        int blk = r - 1664; int mat = blk >> 5;
        const float* src = mat==0?dec : mat==1?lhh : mat==2?tgt : sem;
        unsigned short* dst = mat==0?Xbf : mat==1?Hbf : mat==2?Tbf : Sbf;
        size_t i = ((size_t)(blk&31)*256 + t)*8;
        float4 lo = *(const float4*)&src[i];
        float4 hi = *(const float4*)&src[i+4];
        uint4 p;
        p.x = pk2(lo.x,lo.y); p.y = pk2(lo.z,lo.w);
        p.z = pk2(hi.x,hi.y); p.w = pk2(hi.z,hi.w);
        *(uint4*)&dst[i] = p;
    }
}

// ===== shared 128x128x512 bf16 MFMA tile: C = A @ B^T (async LDS staging, K=64) =====
__device__ __forceinline__ void gemm128_tile(
    const unsigned short* __restrict__ Ab,   // 128 x 512 row-major bf16
    const unsigned short* __restrict__ Bb,   // 128 x 512 row-major bf16
    float* __restrict__ C, int ldc)
{
    __shared__ __align__(16) unsigned short As[128*64];
    __shared__ __align__(16) unsigned short Bs[128*64];
    int t = threadIdx.x;
    int lane = t & 63, wave = t >> 6;
    int wy = wave >> 1, wx = wave & 1;
    int li = lane & 15, quad = lane >> 4;

    floatx4 acc[4][4];
    #pragma unroll
    for (int i=0;i<4;++i)
      #pragma unroll
      for (int j=0;j<4;++j) acc[i][j] = (floatx4)(0.0f);

    for (int kt=0; kt<8; ++kt){
        int k0 = kt*64;
        #pragma unroll
        for (int c=0;c<4;++c){
            int s = c*256 + t;
            int row = s >> 3;
            int kb = (s & 7) ^ (row & 7);
            gl16(&Ab[(size_t)row*512 + k0 + kb*8], &As[(size_t)s*8]);
            gl16(&Bb[(size_t)row*512 + k0 + kb*8], &Bs[(size_t)s*8]);
        }
        __syncthreads();
        #pragma unroll
        for (int ks=0;ks<2;++ks){
            short8 af[4], bg[4];
            #pragma unroll
            for (int i=0;i<4;++i){
                int m = wy*64 + i*16 + li;
                int kb = (ks*4 + quad) ^ (m&7);
                af[i] = *(const short8*)&As[m*64 + kb*8];
            }
            #pragma unroll
            for (int j=0;j<4;++j){
                int h = wx*64 + j*16 + li;
                int kb = (ks*4 + quad) ^ (h&7);
                bg[j] = *(const short8*)&Bs[h*64 + kb*8];
            }
            #pragma unroll
            for (int i=0;i<4;++i)
              #pragma unroll
              for (int j=0;j<4;++j)
                acc[i][j] = __builtin_amdgcn_mfma_f32_16x16x32_bf16(af[i], bg[j], acc[i][j], 0,0,0);
        }
        __syncthreads();
    }
    #pragma unroll
    for (int i=0;i<4;++i)
      #pragma unroll
      for (int j=0;j<4;++j)
        #pragma unroll
        for (int rg=0;rg<4;++rg){
            int m = wy*64 + i*16 + quad*4 + rg;
            int n = wx*64 + j*16 + li;
            C[(size_t)m*ldc + n] = acc[i][j][rg];
        }
}

// ===== K-slice variant: kt in [ktbeg,ktend), atomicAdd combine (for critical-path minis) =====
__device__ __forceinline__ void gemm128_kslice(
    const unsigned short* __restrict__ Ab,
    const unsigned short* __restrict__ Bb,
    float* __restrict__ C, int ldc, int ktbeg, int ktend)
{
    __shared__ __align__(16) unsigned short As[128*64];
    __shared__ __align__(16) unsigned short Bs[128*64];
    int t = threadIdx.x;
    int lane = t & 63, wave = t >> 6;
    int wy = wave >> 1, wx = wave & 1;
    int li = lane & 15, quad = lane >> 4;

    floatx4 acc[4][4];
    #pragma unroll
    for (int i=0;i<4;++i)
      #pragma unroll
      for (int j=0;j<4;++j) acc[i][j] = (floatx4)(0.0f);

    for (int kt=ktbeg; kt<ktend; ++kt){
        int k0 = kt*64;
        #pragma unroll
        for (int c=0;c<4;++c){
            int s = c*256 + t;
            int row = s >> 3;
            int kb = (s & 7) ^ (row & 7);
            gl16(&Ab[(size_t)row*512 + k0 + kb*8], &As[(size_t)s*8]);
            gl16(&Bb[(size_t)row*512 + k0 + kb*8], &Bs[(size_t)s*8]);
        }
        __syncthreads();
        #pragma unroll
        for (int ks=0;ks<2;++ks){
            short8 af[4], bg[4];
            #pragma unroll
            for (int i=0;i<4;++i){
                int m = wy*64 + i*16 + li;
                int kb = (ks*4 + quad) ^ (m&7);
                af[i] = *(const short8*)&As[m*64 + kb*8];
            }
            #pragma unroll
            for (int j=0;j<4;++j){
                int h = wx*64 + j*16 + li;
                int kb = (ks*4 + quad) ^ (h&7);
                bg[j] = *(const short8*)&Bs[h*64 + kb*8];
            }
            #pragma unroll
            for (int i=0;i<4;++i)
              #pragma unroll
              for (int j=0;j<4;++j)
                acc[i][j] = __builtin_amdgcn_mfma_f32_16x16x32_bf16(af[i], bg[j], acc[i][j], 0,0,0);
        }
        __syncthreads();
    }
    #pragma unroll
    for (int i=0;i<4;++i)
      #pragma unroll
      for (int j=0;j<4;++j)
        #pragma unroll
        for (int rg=0;rg<4;++rg){
            int m = wy*64 + i*16 + quad*4 + rg;
            int n = wx*64 + j*16 + li;
            atomicAdd(&C[(size_t)m*ldc + n], acc[i][j][rg]);
        }
}

// fp32-A K-slice (inline cvt staging), atomicAdd combine
__device__ __forceinline__ void gemm128_kslice_f32A(
    const float* __restrict__ Af,
    const unsigned short* __restrict__ Bb,
    float* __restrict__ C, int ldc, int ktbeg, int ktend)
{
    __shared__ __align__(16) unsigned short As[128*64];
    __shared__ __align__(16) unsigned short Bs[128*64];
    int t = threadIdx.x;
    int lane = t & 63, wave = t >> 6;
    int wy = wave >> 1, wx = wave & 1;
    int li = lane & 15, quad = lane >> 4;

    floatx4 acc[4][4];
    #pragma unroll
    for (int i=0;i<4;++i)
      #pragma unroll
      for (int j=0;j<4;++j) acc[i][j] = (floatx4)(0.0f);

    for (int kt=ktbeg; kt<ktend; ++kt){
        int k0 = kt*64;
        #pragma unroll
        for (int c=0;c<4;++c){
            int s = c*256 + t;
            int row = s >> 3;
            int kb = (s & 7) ^ (row & 7);
            gl16(&Bb[(size_t)row*512 + k0 + kb*8], &Bs[(size_t)s*8]);
            const float* src = Af + (size_t)row*512 + k0 + kb*8;
            float4 lo = *(const float4*)src;
            float4 hi = *(const float4*)(src+4);
            uint4 p;
            p.x = pk2(lo.x,lo.y); p.y = pk2(lo.z,lo.w);
            p.z = pk2(hi.x,hi.y); p.w = pk2(hi.z,hi.w);
            *(uint4*)&As[(size_t)s*8] = p;
        }
        __syncthreads();
        #pragma unroll
        for (int ks=0;ks<2;++ks){
            short8 af[4], bg[4];
            #pragma unroll
            for (int i=0;i<4;++i){
                int m = wy*64 + i*16 + li;
                int kb = (ks*4 + quad) ^ (m&7);
                af[i] = *(const short8*)&As[m*64 + kb*8];
            }
            #pragma unroll
            for (int j=0;j<4;++j){
                int h = wx*64 + j*16 + li;
                int kb = (ks*4 + quad) ^ (h&7);
                bg[j] = *(const short8*)&Bs[h*64 + kb*8];
            }
            #pragma unroll
            for (int i=0;i<4;++i)
              #pragma unroll
              for (int j=0;j<4;++j)
                acc[i][j] = __builtin_amdgcn_mfma_f32_16x16x32_bf16(af[i], bg[j], acc[i][j], 0,0,0);
        }
        __syncthreads();
    }
    #pragma unroll
    for (int i=0;i<4;++i)
      #pragma unroll
      for (int j=0;j<4;++j)
        #pragma unroll
        for (int rg=0;rg<4;++rg){
            int m = wy*64 + i*16 + quad*4 + rg;
            int n = wx*64 + j*16 + li;
            atomicAdd(&C[(size_t)m*ldc + n], acc[i][j][rg]);
        }
}

// ---- mega kernel: GRU gates GEMM (24) + GRU-independent bias GEMMs (8) + A cast ----
__global__ __launch_bounds__(256,2) void k_mega(
    const unsigned short* __restrict__ Xbf, const unsigned short* __restrict__ Hbf,
    const unsigned short* __restrict__ Wih_b, const unsigned short* __restrict__ Whh_b,
    float* __restrict__ gx, float* __restrict__ gh,
    const unsigned short* __restrict__ Tbf, const unsigned short* __restrict__ Sbf,
    const unsigned short* __restrict__ Wt_d, const unsigned short* __restrict__ Wp_e,
    float* __restrict__ d_tgt, float* __restrict__ d_se,
    const float* __restrict__ A, unsigned short* __restrict__ Abf)
{
    int blk = blockIdx.x;
    if (blk < 32){
        const unsigned short *Ab, *Bb; float* C; int ldc;
        if (blk < 24){
            int mat = blk / 12, nt = blk % 12;
            Ab = mat ? Hbf : Xbf;
            Bb = (mat ? Whh_b : Wih_b) + (size_t)nt*128*512;
            C = (mat ? gh : gx) + nt*128;
            ldc = 3*H;
        } else {
            int sub = blk - 24; int mat = sub >> 2, nt = sub & 3;
            Ab = mat==0 ? Tbf : Sbf;
            Bb = (mat==0 ? Wt_d : Wp_e) + (size_t)nt*128*512;
            C = (mat==0 ? d_tgt : d_se) + nt*128;
            ldc = H;
        }
        gemm128_tile(Ab, Bb, C, ldc);
    } else {
        int t = threadIdx.x;
        size_t i = ((size_t)(blk-32)*256 + t)*8;
        float4 lo = *(const float4*)&A[i];
        float4 hi = *(const float4*)&A[i+4];
        uint4 p;
        p.x = pk2(lo.x,lo.y); p.y = pk2(lo.z,lo.w);
        p.z = pk2(hi.x,hi.y); p.w = pk2(hi.z,hi.w);
        *(uint4*)&Abf[i] = p;
    }
}

// ---- GRU elementwise gates ----
__global__ __launch_bounds__(256) void k_gru_gate(const float* __restrict__ gx,
    const float* __restrict__ gh, const float* __restrict__ lhh,
    const float* __restrict__ bih, const float* __restrict__ bhh,
    float* __restrict__ out_hh, unsigned short* __restrict__ hnew_bf)
{
    int idx = blockIdx.x*256 + threadIdx.x;   // 0..65535
    int b = idx >> 9, k = idx & 511;
    const float* gxb = gx + (size_t)b*(3*H);
    const float* ghb = gh + (size_t)b*(3*H);
    float r = sigmoidf_(gxb[k]     + bih[k]     + ghb[k]     + bhh[k]);
    float z = sigmoidf_(gxb[H+k]   + bih[H+k]   + ghb[H+k]   + bhh[H+k]);
    float n = tanhf(gxb[2*H+k] + bih[2*H+k] + r*(ghb[2*H+k] + bhh[2*H+k]));
    float h = (1.f-z)*n + z*lhh[idx];
    out_hh[idx] = h;
    hnew_bf[idx] = (unsigned short)f2bf1(h);
}

// ---- enc bias GEMM: K-split x4 (grid 16) to shorten the GRU critical path ----
__global__ __launch_bounds__(256,2) void k_bias_enc(
    const unsigned short* __restrict__ HNbf, const unsigned short* __restrict__ We_d,
    float* __restrict__ d_enc)
{
    int nt = blockIdx.x & 3, ks = blockIdx.x >> 2;
    gemm128_kslice(HNbf, We_d + (size_t)nt*128*512, d_enc + nt*128, H, ks*2, ks*2+2);
}

// ---- pointer biases GEMM: K-split x4 (grid 32), fp32 ctx/ctxt staged inline ----
__global__ __launch_bounds__(256,2) void k_dptr_gemm(
    const float* __restrict__ ctx, const float* __restrict__ ctxt,
    const unsigned short* __restrict__ Wp_c,
    float* __restrict__ d_pe, float* __restrict__ d_pt)
{
    int blk = blockIdx.x;
    int mat = blk >> 4, sub = blk & 15;
    int nt = sub & 3, ks = sub >> 2;
    const float* Af = mat ? ctxt : ctx;
    const unsigned short* Bb = Wp_c + (size_t)nt*128*512;
    float* C = (mat ? d_pt : d_pe) + nt*128;
    gemm128_kslice_f32A(Af, Bb, C, H, ks*2, ks*2+2);
}

// ---- fused enc+tgt scores: grid 512 (b x nt), ht loop inside, single-buffer K=64 ----
// (the R1 core: best measured structure, 104us, 0 conflicts)
template<bool BF16A>
__global__ __launch_bounds__(256,2) void k_scores_fused(
    const float* __restrict__ Af, const unsigned short* __restrict__ Abf,
    const unsigned short* __restrict__ We, const unsigned short* __restrict__ Wt,
    const float* __restrict__ d_enc, const float* __restrict__ d_tgt,
    const float* __restrict__ enc_v, const float* __restrict__ tgt_v,
    float* __restrict__ sc_e, float* __restrict__ sc_t)
{
    __shared__ __align__(16) unsigned short As[128*64];
    __shared__ __align__(16) unsigned short Be[128*64];
    __shared__ __align__(16) unsigned short Bt[128*64];
    __shared__ float red_e[2][128], red_t[2][128];
    int blk = blockIdx.x;
    int b = blk >> 2; int nt = blk & 3;
    int n0 = nt*128;
    int t = threadIdx.x;
    int lane = t & 63, wave = t >> 6;
    int wy = wave >> 1, wx = wave & 1;
    int li = lane & 15, quad = lane >> 4;

    float nse[4][4], nst[4][4];
    #pragma unroll
    for (int i=0;i<4;++i)
      #pragma unroll
      for (int rg=0;rg<4;++rg){ nse[i][rg]=0.f; nst[i][rg]=0.f; }

    for (int ht=0; ht<4; ++ht){
        int hb = ht*128;
        floatx4 acc_e[4][4], acc_t[4][4];
        #pragma unroll
        for (int i=0;i<4;++i)
          #pragma unroll
          for (int j=0;j<4;++j){ acc_e[i][j]=(floatx4)(0.0f); acc_t[i][j]=(floatx4)(0.0f); }

        for (int kt=0; kt<8; ++kt){
            int k0 = kt*64;
            #pragma unroll
            for (int c=0;c<4;++c){
                int s = c*256 + t;
                int row = s >> 3;
                int kb = (s & 7) ^ (row & 7);
                if constexpr (BF16A){
                    gl16(&Abf[(size_t)(b*N+n0+row)*H + k0 + kb*8], &As[(size_t)s*8]);
                } else {
                    const float* src = Af + (size_t)(b*N+n0+row)*H + k0 + kb*8;
                    float4 lo = *(const float4*)src;
                    float4 hi = *(const float4*)(src+4);
                    uint4 p;
                    p.x = pk2(lo.x,lo.y); p.y = pk2(lo.z,lo.w);
                    p.z = pk2(hi.x,hi.y); p.w = pk2(hi.z,hi.w);
                    *(uint4*)&As[(size_t)s*8] = p;
                }
                gl16(&We[(size_t)(hb+row)*H + k0 + kb*8], &Be[(size_t)s*8]);
                gl16(&Wt[(size_t)(hb+row)*H + k0 + kb*8], &Bt[(size_t)s*8]);
            }
            __syncthreads();
            #pragma unroll
            for (int ks=0;ks<2;++ks){
                short8 af[4], be[4], bt[4];
                #pragma unroll
                for (int i=0;i<4;++i){
                    int m = wy*64 + i*16 + li;
                    int kb = (ks*4 + quad) ^ (m&7);
                    af[i] = *(const short8*)&As[m*64 + kb*8];
                }
                #pragma unroll
                for (int j=0;j<4;++j){
                    int h = wx*64 + j*16 + li;
                    int kb = (ks*4 + quad) ^ (h&7);
                    be[j] = *(const short8*)&Be[h*64 + kb*8];
                    bt[j] = *(const short8*)&Bt[h*64 + kb*8];
                }
                #pragma unroll
                for (int i=0;i<4;++i)
                  #pragma unroll
                  for (int j=0;j<4;++j){
                    acc_e[i][j] = __builtin_amdgcn_mfma_f32_16x16x32_bf16(af[i], be[j], acc_e[i][j], 0,0,0);
                    acc_t[i][j] = __builtin_amdgcn_mfma_f32_16x16x32_bf16(af[i], bt[j], acc_t[i][j], 0,0,0);
                  }
            }
            __syncthreads();
        }
        // epilogue for this h-tile: accumulate v*tanh(S+d) into per-lane partials
        #pragma unroll
        for (int j=0;j<4;++j){
            int hm = hb + wx*64 + j*16 + li;
            float dje = d_enc[b*H+hm], vje = enc_v[hm];
            float djt = d_tgt[b*H+hm], vjt = tgt_v[hm];
            #pragma unroll
            for (int i=0;i<4;++i)
              #pragma unroll
              for (int rg=0;rg<4;++rg){
                nse[i][rg] += vje * fast_tanh(acc_e[i][j][rg] + dje);
                nst[i][rg] += vjt * fast_tanh(acc_t[i][j][rg] + djt);
              }
        }
    }
    #pragma unroll
    for (int off=1; off<16; off<<=1)
      #pragma unroll
      for (int i=0;i<4;++i)
        #pragma unroll
        for (int rg=0;rg<4;++rg){
          nse[i][rg] += __shfl_xor(nse[i][rg], off);
          nst[i][rg] += __shfl_xor(nst[i][rg], off);
        }
    if (li==0){
        #pragma unroll
        for (int i=0;i<4;++i)
          #pragma unroll
          for (int rg=0;rg<4;++rg){
            red_e[wx][wy*64 + i*16 + quad*4 + rg] = nse[i][rg];
            red_t[wx][wy*64 + i*16 + quad*4 + rg] = nst[i][rg];
          }
    }
    __syncthreads();
    if (t < 128){
        sc_e[b*N + n0 + t] = red_e[0][t] + red_e[1][t];
    } else {
        int r2 = t - 128;
        sc_t[b*N + n0 + r2] = red_t[0][r2] + red_t[1][r2];
    }
}

// ---- fused softmax + context: grid 512 (b x col-quarter), direct store ----
template<bool BF16A>
__global__ __launch_bounds__(256) void k_smax_ctx(
    const float* __restrict__ Af, const unsigned short* __restrict__ Abf,
    const float* __restrict__ sc_e, const float* __restrict__ sc_t,
    float* __restrict__ ctx, float* __restrict__ ctxt)
{
    __shared__ float we[512], wt[512];
    __shared__ float buf[256];
    __shared__ float red[4][64][4];
    int b = blockIdx.x >> 2, q = blockIdx.x & 3;
    int t = threadIdx.x;

    {
        float x0 = sc_e[b*N+t], x1 = sc_e[b*N+t+256];
        float m = fmaxf(x0,x1);
        buf[t]=m; __syncthreads();
        for (int s2=128;s2>0;s2>>=1){ if(t<s2) buf[t]=fmaxf(buf[t],buf[t+s2]); __syncthreads(); }
        m = buf[0]; __syncthreads();
        float e0 = __expf(x0-m), e1 = __expf(x1-m);
        buf[t]=e0+e1; __syncthreads();
        for (int s2=128;s2>0;s2>>=1){ if(t<s2) buf[t]+=buf[t+s2]; __syncthreads(); }
        float inv = 1.0f/buf[0]; __syncthreads();
        we[t]=e0*inv; we[t+256]=e1*inv;
    }
    {
        float x0 = sc_t[b*N+t], x1 = sc_t[b*N+t+256];
        float m = fmaxf(x0,x1);
        buf[t]=m; __syncthreads();
        for (int s2=128;s2>0;s2>>=1){ if(t<s2) buf[t]=fmaxf(buf[t],buf[t+s2]); __syncthreads(); }
        m = buf[0]; __syncthreads();
        float e0 = __expf(x0-m), e1 = __expf(x1-m);
        buf[t]=e0+e1; __syncthreads();
        for (int s2=128;s2>0;s2>>=1){ if(t<s2) buf[t]+=buf[t+s2]; __syncthreads(); }
        float inv = 1.0f/buf[0]; __syncthreads();
        wt[t]=e0*inv; wt[t+256]=e1*inv;
    }
    __syncthreads();

    int p = t & 63, nq = t >> 6;
    int cp = q*64 + p;
    float ae0=0.f, ae1=0.f, at0=0.f, at1=0.f;
    if constexpr (BF16A){
        const unsigned* base = (const unsigned*)Abf + (size_t)(b*N + nq*128)*(H/2) + cp;
        for (int n=0;n<128;++n){
            unsigned u = base[(size_t)n*(H/2)];
            float lo = __uint_as_float(u<<16);
            float hi = __uint_as_float(u & 0xFFFF0000u);
            float e = we[nq*128+n], g = wt[nq*128+n];
            ae0 += e*lo; ae1 += e*hi; at0 += g*lo; at1 += g*hi;
        }
    } else {
        const float* base = Af + (size_t)(b*N + nq*128)*H + 2*cp;
        for (int n=0;n<128;++n){
            float2 v = *(const float2*)&base[(size_t)n*H];
            float e = we[nq*128+n], g = wt[nq*128+n];
            ae0 += e*v.x; ae1 += e*v.y; at0 += g*v.x; at1 += g*v.y;
        }
    }
    red[nq][p][0]=ae0; red[nq][p][1]=ae1; red[nq][p][2]=at0; red[nq][p][3]=at1;
    __syncthreads();
    if (t < 64){
        float s0=0.f,s1=0.f,s2=0.f,s3=0.f;
        #pragma unroll
        for (int k2=0;k2<4;++k2){
            s0+=red[k2][t][0]; s1+=red[k2][t][1]; s2+=red[k2][t][2]; s3+=red[k2][t][3];
        }
        int c2 = q*64 + t;
        ctx [(size_t)b*H + 2*c2]   = s0;
        ctx [(size_t)b*H + 2*c2+1] = s1;
        ctxt[(size_t)b*H + 2*c2]   = s2;
        ctxt[(size_t)b*H + 2*c2+1] = s3;
    }
}

// ---- pointer probs: grid 512 (b x nt), TWO h-tiles of Wp per A-stage ----
// Matches scores' staged-bytes:MFMA ratio (48KB : 64 MFMA/wave per kt) so the
// shared A staging is amortized over 2 GEMM tiles; ht-pair loop = 2 iters.
template<bool BF16A>
__global__ __launch_bounds__(256,2) void k_probs_mfma(
    const float* __restrict__ Af, const unsigned short* __restrict__ Abf,
    const unsigned short* __restrict__ Wp,
    const float* __restrict__ d_pe, const float* __restrict__ d_pt,
    const float* __restrict__ d_se,
    const float* __restrict__ ptr_v, float* __restrict__ probs)
{
    __shared__ __align__(16) unsigned short As[128*64];
    __shared__ __align__(16) unsigned short B0[128*64];
    __shared__ __align__(16) unsigned short B1[128*64];
    __shared__ float red[2][128];
    int blk = blockIdx.x;
    int b = blk >> 2; int nt = blk & 3;
    int n0 = nt*128;

    int t = threadIdx.x;
    int lane = t & 63, wave = t >> 6;
    int wy = wave >> 1, wx = wave & 1;
    int li = lane & 15, quad = lane >> 4;

    float nsum[4][4];
    #pragma unroll
    for (int i=0;i<4;++i){ nsum[i][0]=0.f;nsum[i][1]=0.f;nsum[i][2]=0.f;nsum[i][3]=0.f; }

    for (int hp=0; hp<2; ++hp){
        int hb0 = hp*256;            // two 128-row Wp tiles: hb0, hb0+128
        floatx4 acc0[4][4], acc1[4][4];
        #pragma unroll
        for (int i=0;i<4;++i)
          #pragma unroll
          for (int j=0;j<4;++j){ acc0[i][j]=(floatx4)(0.0f); acc1[i][j]=(floatx4)(0.0f); }

        for (int kt=0; kt<8; ++kt){
            int k0 = kt*64;
            #pragma unroll
            for (int c=0;c<4;++c){
                int s = c*256 + t;
                int row = s >> 3;
                int kb = (s & 7) ^ (row & 7);
                if constexpr (BF16A){
                    gl16(&Abf[(size_t)(b*N+n0+row)*H + k0 + kb*8], &As[(size_t)s*8]);
                } else {
                    const float* src = Af + (size_t)(b*N+n0+row)*H + k0 + kb*8;
                    float4 lo = *(const float4*)src;
                    float4 hi = *(const float4*)(src+4);
                    uint4 p;
                    p.x = pk2(lo.x,lo.y); p.y = pk2(lo.z,lo.w);
                    p.z = pk2(hi.x,hi.y); p.w = pk2(hi.z,hi.w);
                    *(uint4*)&As[(size_t)s*8] = p;
                }
                gl16(&Wp[(size_t)(hb0+row)*H     + k0 + kb*8], &B0[(size_t)s*8]);
                gl16(&Wp[(size_t)(hb0+128+row)*H + k0 + kb*8], &B1[(size_t)s*8]);
            }
            __syncthreads();
            #pragma unroll
            for (int ks=0;ks<2;++ks){
                short8 af[4], bg0[4], bg1[4];
                #pragma unroll
                for (int i=0;i<4;++i){
                    int m = wy*64 + i*16 + li;
                    int kb = (ks*4 + quad) ^ (m&7);
                    af[i] = *(const short8*)&As[m*64 + kb*8];
                }
                #pragma unroll
                for (int j=0;j<4;++j){
                    int h = wx*64 + j*16 + li;
                    int kb = (ks*4 + quad) ^ (h&7);
                    bg0[j] = *(const short8*)&B0[h*64 + kb*8];
                    bg1[j] = *(const short8*)&B1[h*64 + kb*8];
                }
                #pragma unroll
                for (int i=0;i<4;++i)
                  #pragma unroll
                  for (int j=0;j<4;++j){
                    acc0[i][j] = __builtin_amdgcn_mfma_f32_16x16x32_bf16(af[i], bg0[j], acc0[i][j], 0,0,0);
                    acc1[i][j] = __builtin_amdgcn_mfma_f32_16x16x32_bf16(af[i], bg1[j], acc1[i][j], 0,0,0);
                  }
            }
            __syncthreads();
        }
        // epilogue for both h-subtiles of this pair
        #pragma unroll
        for (int sub=0; sub<2; ++sub){
            #pragma unroll
            for (int j=0;j<4;++j){
                int hm = hb0 + sub*128 + wx*64 + j*16 + li;
                float se = d_se[b*H + hm];
                float de = d_pe[b*H + hm] + se;
                float dt = d_pt[b*H + hm] + se;
                float vj = ptr_v[hm];
                #pragma unroll
                for (int i=0;i<4;++i)
                  #pragma unroll
                  for (int rg=0;rg<4;++rg){
                    float s = sub ? acc1[i][j][rg] : acc0[i][j][rg];
                    nsum[i][rg] += vj * (5.0f*fast_tanh(s + de) + fast_tanh(s + dt));
                  }
            }
        }
    }
    #pragma unroll
    for (int off=1; off<16; off<<=1)
      #pragma unroll
      for (int i=0;i<4;++i)
        #pragma unroll
        for (int rg=0;rg<4;++rg)
          nsum[i][rg] += __shfl_xor(nsum[i][rg], off);
    if (li==0){
        #pragma unroll
        for (int i=0;i<4;++i)
          #pragma unroll
          for (int rg=0;rg<4;++rg)
            red[wx][wy*64 + i*16 + quad*4 + rg] = nsum[i][rg];
    }
    __syncthreads();
    if (t < 128)
        probs[b*N + n0 + t] = red[0][t] + red[1][t];
}

extern "C" void kernel_launch(void* const* d_in, const int* in_sizes, int n_in,
                              void* d_out, int out_size, void* d_ws, size_t ws_size,
                              hipStream_t stream)
{
    (void)in_sizes; (void)n_in; (void)out_size;
    const float* A    = (const float*)d_in[0];
    const float* sem  = (const float*)d_in[1];
    const float* dec  = (const float*)d_in[2];
    const float* tgt  = (const float*)d_in[3];
    const float* lhh  = (const float*)d_in[4];
    const float* ptrv = (const float*)d_in[5];
    const float* ptrW = (const float*)d_in[6];
    const float* encv = (const float*)d_in[7];
    const float* encW = (const float*)d_in[8];
    const float* tgtv = (const float*)d_in[9];
    const float* tgtW = (const float*)d_in[10];
    const float* wih  = (const float*)d_in[11];
    const float* whh  = (const float*)d_in[12];
    const float* bih  = (const float*)d_in[13];
    const float* bhh  = (const float*)d_in[14];

    float* probs_out = (float*)d_out;
    float* hh_out    = (float*)d_out + B*N;

    float* ws = (float*)d_ws;
    const size_t S = (size_t)B*H;          // 65536
    float* d_enc = ws;
    float* d_tgt = ws + S;
    float* d_se  = ws + 2*S;
    float* sc_e  = ws + 3*S;
    float* sc_t  = ws + 4*S;
    float* ctx   = ws + 5*S;
    float* ctxt  = ws + 6*S;
    float* d_pe  = ws + 9*S;
    float* d_pt  = ws + 10*S;
    float* gx    = ws + 11*S;              // 3S
    float* gh    = ws + 14*S;              // 3S
    unsigned short* bfb  = (unsigned short*)(ws + 17*S);
    const size_t WH = (size_t)H*H;         // 262144
    const size_t WG = (size_t)3*H*H;
    unsigned short* We_s  = bfb;
    unsigned short* Wt_s  = We_s + WH;
    unsigned short* Wp_s  = Wt_s + WH;
    unsigned short* We_d  = Wp_s + WH;
    unsigned short* Wt_d  = We_d + WH;
    unsigned short* Wp_c  = Wt_d + WH;
    unsigned short* Wp_e  = Wp_c + WH;
    unsigned short* Wih_b = Wp_e + WH;
    unsigned short* Whh_b = Wih_b + WG;
    unsigned short* Xbf   = Whh_b + WG;
    unsigned short* Hbf   = Xbf + S;
    unsigned short* Tbf   = Hbf + S;
    unsigned short* Sbf   = Tbf + S;
    unsigned short* HNbf  = Sbf + S;
    unsigned short* Abf   = HNbf + S;

    const size_t need_full = 17*S*sizeof(float)
        + (7*WH + 2*WG + 5*S + (size_t)B*N*H) * sizeof(unsigned short);
    const bool big = ws_size >= need_full;

    // K-split minis combine via atomics -> zero their outputs (tiny, overlaps cast)
    hipMemsetAsync(d_enc, 0, S*sizeof(float), stream);
    hipMemsetAsync(d_pe, 0, 2*S*sizeof(float), stream);

    // 1. weight + small-activation casts (vectorized: 4 rows/block)
    k_cast_small<<<1792, 256, 0, stream>>>(encW, tgtW, ptrW, wih, whh,
        dec, lhh, tgt, sem,
        We_s, Wt_s, Wp_s, We_d, Wt_d, Wp_c, Wp_e, Wih_b, Whh_b,
        Xbf, Hbf, Tbf, Sbf);

    // 2. GRU GEMMs + GRU-independent bias GEMMs, hidden under the A cast
    int castA_blocks = big ? (int)(((size_t)B*N*H)/(256*8)) : 0;   // 16384
    k_mega<<<32 + castA_blocks, 256, 0, stream>>>(Xbf, Hbf, Wih_b, Whh_b, gx, gh,
        Tbf, Sbf, Wt_d, Wp_e, d_tgt, d_se, A, Abf);

    // 3. GRU gates
    k_gru_gate<<<256, 256, 0, stream>>>(gx, gh, lhh, bih, bhh, hh_out, HNbf);

    // 4. d_enc, K-split x4 (16 blocks)
    k_bias_enc<<<16, 256, 0, stream>>>(HNbf, We_d, d_enc);

    // 5. fused scores (R1 single-buffer core), direct store
    if (big)
        k_scores_fused<true ><<<512, 256, 0, stream>>>(A, Abf, We_s, Wt_s, d_enc, d_tgt, encv, tgtv, sc_e, sc_t);
    else
        k_scores_fused<false><<<512, 256, 0, stream>>>(A, Abf, We_s, Wt_s, d_enc, d_tgt, encv, tgtv, sc_e, sc_t);

    // 6. softmax + context fused, direct store
    if (big)
        k_smax_ctx<true ><<<512, 256, 0, stream>>>(A, Abf, sc_e, sc_t, ctx, ctxt);
    else
        k_smax_ctx<false><<<512, 256, 0, stream>>>(A, Abf, sc_e, sc_t, ctx, ctxt);

    // 7. pointer bias GEMMs, K-split x4 (32 blocks)
    k_dptr_gemm<<<32, 256, 0, stream>>>(ctx, ctxt, Wp_c, d_pe, d_pt);

    // 8. pointer probs (paired h-tiles share A staging), direct store
    if (big)
        k_probs_mfma<true ><<<512, 256, 0, stream>>>(A, Abf, Wp_s, d_pe, d_pt, d_se, ptrv, probs_out);
    else
        k_probs_mfma<false><<<512, 256, 0, stream>>>(A, Abf, Wp_s, d_pe, d_pt, d_se, ptrv, probs_out);
}